// Round 17
// baseline (241.804 us; speedup 1.0000x reference)
//
#include <hip/hip_runtime.h>
#include <math.h>

#define NN 50000
#define EE 600000
#define GG 250
#define HH 128

// prep_k grid split
#define B_CVT  6250
#define B_W    384
#define B_ROOT 196
#define B_ZD   196
#define B_ZH   125

typedef __attribute__((ext_vector_type(8))) short s16x8;
typedef __attribute__((ext_vector_type(8))) unsigned short u16x8;
typedef __attribute__((ext_vector_type(4))) unsigned short u16x4;
typedef __attribute__((ext_vector_type(16))) signed char s8x16;
typedef __attribute__((ext_vector_type(4))) float f32x4;
typedef __attribute__((ext_vector_type(2))) float f32x2;

__device__ __forceinline__ float b2f(unsigned short u) {
  union { unsigned int i; float f; } v; v.i = ((unsigned int)u) << 16; return v.f;
}
__device__ __forceinline__ unsigned short f2b(float f) {
  union { float f; unsigned int i; } v; v.f = f;
  unsigned int x = v.i;
  unsigned int r = (x + 0x7FFFu + ((x >> 16) & 1u)) >> 16;   // RNE, finite inputs
  return (unsigned short)r;
}

// ---------- fused prep: cvt_x(bf16+fp8) | cvtW(frag layout) | root | zero-deg | zero-hg ----------
// WT2 layout: idx = L*32768 + w*4096 + m*2048 + kk*512 + lane*8 + j
__global__ __launch_bounds__(256) void prep_k(
    const float* __restrict__ x, unsigned short* __restrict__ xb,
    unsigned char* __restrict__ xq,
    const float* __restrict__ W0, const float* __restrict__ W1,
    const float* __restrict__ W2, const float* __restrict__ W3,
    const float* __restrict__ W4, const float* __restrict__ W5,
    unsigned short* __restrict__ WT,
    int* __restrict__ deg,
    const int* __restrict__ batch, int* __restrict__ root,
    float* __restrict__ hg) {
  int b = blockIdx.x, tid = threadIdx.x;
  if (b < B_CVT) {
    int i = b * 256 + tid;                       // x4 floats
    float4 v = *(const float4*)&x[i * 4];
    u16x4 o; o[0] = f2b(v.x); o[1] = f2b(v.y); o[2] = f2b(v.z); o[3] = f2b(v.w);
    *(u16x4*)&xb[i * 4] = o;
    int pk = __builtin_amdgcn_cvt_pk_fp8_f32(v.x, v.y, 0, false);
    pk = __builtin_amdgcn_cvt_pk_fp8_f32(v.z, v.w, pk, true);
    *(int*)&xq[i * 4] = pk;
  } else if (b < B_CVT + B_W) {
    int i = (b - B_CVT) * 256 + tid;             // 0..98303
    int j = i & 7, lane = (i >> 3) & 63, kk = (i >> 9) & 3;
    int m = (i >> 11) & 1, w = (i >> 12) & 7, L = i >> 15;
    int sel = L * 2 + m;
    const float* W = (sel == 0) ? W0 : (sel == 1) ? W1 : (sel == 2) ? W2
                     : (sel == 3) ? W3 : (sel == 4) ? W4 : W5;
    int col = w * 16 + (lane & 15);
    int k = kk * 32 + ((lane >> 4) & 3) * 8 + j;
    WT[i] = f2b(W[k * 128 + col]);
  } else if (b < B_CVT + B_W + B_ROOT) {
    int n = (b - B_CVT - B_W) * 256 + tid;
    if (n < NN) {
      int bg = batch[n];
      if (n == 0 || batch[n - 1] != bg) root[bg] = n;
    }
  } else if (b < B_CVT + B_W + B_ROOT + B_ZD) {
    int n = (b - B_CVT - B_W - B_ROOT) * 256 + tid;
    if (n < NN) deg[n] = 0;
  } else {
    int i = (b - B_CVT - B_W - B_ROOT - B_ZD) * 256 + tid;   // < 32000
    hg[i] = 0.f;
  }
}

// ---------- histogram ----------
__global__ void hist_k(const int* __restrict__ dst, int* __restrict__ deg) {
  int e = blockIdx.x * 256 + threadIdx.x;
  if (e < EE) atomicAdd(&deg[dst[e]], 1);
}

// ---------- scan, phase 1 ----------
__global__ __launch_bounds__(1024) void scan1_k(const int* __restrict__ deg,
                                                int* __restrict__ excl,
                                                int* __restrict__ bsum) {
  __shared__ int sums[16];
  int tid = threadIdx.x;
  int i = blockIdx.x * 1024 + tid;
  int v = (i < NN) ? deg[i] : 0;
  int lane = tid & 63, wid = tid >> 6;
  int x = v;
  #pragma unroll
  for (int d = 1; d < 64; d <<= 1) { int y = __shfl_up(x, d); if (lane >= d) x += y; }
  if (lane == 63) sums[wid] = x;
  __syncthreads();
  if (wid == 0) {
    int s = (lane < 16) ? sums[lane] : 0;
    #pragma unroll
    for (int d = 1; d < 16; d <<= 1) { int y = __shfl_up(s, d); if (lane >= d) s += y; }
    if (lane < 16) sums[lane] = s;
  }
  __syncthreads();
  int ex = (wid ? sums[wid - 1] : 0) + x - v;
  if (i < NN) excl[i] = ex;
  if (tid == 1023) bsum[blockIdx.x] = sums[15];
}

// ---------- scan, phase 2+3 fused ----------
__global__ __launch_bounds__(256) void scanB_k(const int* __restrict__ excl,
                                               const int* __restrict__ bsum,
                                               int* __restrict__ rowptr,
                                               int* __restrict__ wp) {
  __shared__ int sboff[64];
  int tid = threadIdx.x;
  if (tid < 64) {
    int v = (tid < 49) ? bsum[tid] : 0;
    int x = v;
    #pragma unroll
    for (int d = 1; d < 64; d <<= 1) { int y = __shfl_up(x, d); if (tid >= d) x += y; }
    sboff[tid] = x - v;
  }
  __syncthreads();
  int i = blockIdx.x * 256 + tid;
  if (i < NN) {
    int r = excl[i] + sboff[i >> 10];
    rowptr[i] = r; wp[i] = r;
  }
  if (i == 0) rowptr[NN] = EE;
}

__global__ void scatter_k(const int* __restrict__ src, const int* __restrict__ dst,
                          int* __restrict__ wp, int* __restrict__ eidx) {
  int e = blockIdx.x * 256 + threadIdx.x;
  if (e < EE) {
    int p = atomicAdd(&wp[dst[e]], 1);
    eidx[p] = src[e];
  }
}

// ---------- fused layer: fp8 pair-gather-mean -> LDS, MFMA, L2norm, relu, dual store ----------
// 512 threads / 8 waves / 64 rows. Gather: 16-lane group = 2 edges in parallel
// (8 lanes x 16B each = full fp8 row), 4 pair-loads in flight = 8 edges/group.
// Self path bf16. Outputs bf16 (next self) + fp8 (next gather).
// Layer 3: hout=nullptr -> pool only, no stores.
__global__ __launch_bounds__(512) void layer_k(
    const unsigned short* __restrict__ hb,
    const unsigned char* __restrict__ hq,
    const int* __restrict__ rowptr, const int* __restrict__ eidx,
    const unsigned short* __restrict__ WT2, const float* __restrict__ bl,
    unsigned short* __restrict__ hout, unsigned char* __restrict__ houtq,
    float* __restrict__ hgmax) {
  __shared__ unsigned short sAgg[64 * 128];   // 16 KB (reused as bf16 out)
  __shared__ unsigned short sH[64 * 128];     // 16 KB (reused as fp8 out)
  __shared__ float sred[8][64];
  __shared__ float sinv[64];
  int tid = threadIdx.x;
  int r0 = blockIdx.x * 64;
  int lane = tid & 63, w = tid >> 6;
  int l16 = lane & 15, hi = lane >> 4;
  bool doout = (hout != nullptr);

  // ---- weights & bias (issue first) ----
  s16x8 wf[8];
  #pragma unroll
  for (int f = 0; f < 8; ++f)
    wf[f] = *(const s16x8*)&WT2[w * 4096 + f * 512 + lane * 8];
  float bb = bl[w * 16 + l16];

  // ---- gather phase: 32 groups of 16 lanes, 2 nodes each; 2 edges/group in parallel ----
  {
    int gid = tid >> 4, gl = tid & 15;
    int base = (lane >> 4) << 4;              // group's base lane within wave
    int half = gl >> 3, hl = gl & 7;
    #pragma unroll 1
    for (int s = 0; s < 2; ++s) {
      int rl = gid * 2 + s;
      int node = r0 + rl; if (node > NN - 1) node = NN - 1;
      int st = rowptr[node], en = rowptr[node + 1];
      u16x8 own = *(const u16x8*)&hb[node * 128 + gl * 8];
      *(u16x8*)&sH[rl * 128 + ((gl ^ (rl & 7)) * 8)] = own;
      float acc[16];
      #pragma unroll
      for (int j = 0; j < 16; ++j) acc[j] = 0.f;
      for (int c = st; c < en; c += 16) {
        int ecl = c + gl; if (ecl > en - 1) ecl = en - 1;
        int myidx = eidx[ecl];                // coalesced 64B, covers 16 edges
        #pragma unroll
        for (int p = 0; p < 16; p += 8) {
          if (c + p < en) {
            uint4 rv[4];
            float msk[4];
            #pragma unroll
            for (int i = 0; i < 4; ++i) {
              int erel = p + 2 * i + half;    // <= 15 by construction
              int sidx = __shfl(myidx, base + erel);
              rv[i] = *(const uint4*)&hq[sidx * 128 + hl * 16];
              msk[i] = (c + erel < en) ? 1.f : 0.f;
            }
            #pragma unroll
            for (int i = 0; i < 4; ++i) {
              float mk = msk[i];
              f32x2 p0;
              p0 = __builtin_amdgcn_cvt_pk_f32_fp8(rv[i].x, false);
              acc[0] = fmaf(mk, p0.x, acc[0]);  acc[1] = fmaf(mk, p0.y, acc[1]);
              p0 = __builtin_amdgcn_cvt_pk_f32_fp8(rv[i].x, true);
              acc[2] = fmaf(mk, p0.x, acc[2]);  acc[3] = fmaf(mk, p0.y, acc[3]);
              p0 = __builtin_amdgcn_cvt_pk_f32_fp8(rv[i].y, false);
              acc[4] = fmaf(mk, p0.x, acc[4]);  acc[5] = fmaf(mk, p0.y, acc[5]);
              p0 = __builtin_amdgcn_cvt_pk_f32_fp8(rv[i].y, true);
              acc[6] = fmaf(mk, p0.x, acc[6]);  acc[7] = fmaf(mk, p0.y, acc[7]);
              p0 = __builtin_amdgcn_cvt_pk_f32_fp8(rv[i].z, false);
              acc[8] = fmaf(mk, p0.x, acc[8]);  acc[9] = fmaf(mk, p0.y, acc[9]);
              p0 = __builtin_amdgcn_cvt_pk_f32_fp8(rv[i].z, true);
              acc[10] = fmaf(mk, p0.x, acc[10]); acc[11] = fmaf(mk, p0.y, acc[11]);
              p0 = __builtin_amdgcn_cvt_pk_f32_fp8(rv[i].w, false);
              acc[12] = fmaf(mk, p0.x, acc[12]); acc[13] = fmaf(mk, p0.y, acc[13]);
              p0 = __builtin_amdgcn_cvt_pk_f32_fp8(rv[i].w, true);
              acc[14] = fmaf(mk, p0.x, acc[14]); acc[15] = fmaf(mk, p0.y, acc[15]);
            }
          }
        }
      }
      // combine the two half-group partial sums (different edges, same cols)
      #pragma unroll
      for (int j = 0; j < 16; ++j) acc[j] += __shfl_xor(acc[j], 8);
      int cnt = en - st;
      float inv = 1.f / (float)(cnt > 0 ? cnt : 1);
      // lane covers cols hl*16..hl*16+15 -> units 2*hl (half 0) / 2*hl+1 (half 1)
      u16x8 o;
      int jb = half * 8;
      #pragma unroll
      for (int j = 0; j < 8; ++j) o[j] = f2b(acc[jb + j] * inv);
      int u = 2 * hl + half;
      *(u16x8*)&sAgg[rl * 128 + ((u ^ (rl & 7)) * 8)] = o;
    }
  }
  __syncthreads();

  // ---- MFMA: 4 row-tiles x this wave's col-tile ----
  f32x4 acc[4];
  #pragma unroll
  for (int rt = 0; rt < 4; ++rt) acc[rt] = (f32x4){0.f, 0.f, 0.f, 0.f};
  #pragma unroll
  for (int kk = 0; kk < 4; ++kk) {
    int au = ((kk * 4 + hi) ^ (l16 & 7)) * 8;
    #pragma unroll
    for (int rt = 0; rt < 4; ++rt) {
      s16x8 a = *(const s16x8*)&sAgg[(rt * 16 + l16) * 128 + au];
      s16x8 h = *(const s16x8*)&sH[(rt * 16 + l16) * 128 + au];
      acc[rt] = __builtin_amdgcn_mfma_f32_16x16x32_bf16(a, wf[kk], acc[rt], 0, 0, 0);
      acc[rt] = __builtin_amdgcn_mfma_f32_16x16x32_bf16(h, wf[4 + kk], acc[rt], 0, 0, 0);
    }
  }

  // ---- bias + partial row-norm (this wave's 16 cols) ----
  float v[4][4];
  #pragma unroll
  for (int rt = 0; rt < 4; ++rt) {
    float ss[4];
    #pragma unroll
    for (int i = 0; i < 4; ++i) {
      float t = acc[rt][i] + bb;
      v[rt][i] = t;
      ss[i] = t * t;
    }
    #pragma unroll
    for (int m = 1; m < 16; m <<= 1) {
      #pragma unroll
      for (int i = 0; i < 4; ++i) ss[i] += __shfl_xor(ss[i], m);
    }
    if (l16 == 0) {
      #pragma unroll
      for (int i = 0; i < 4; ++i) sred[w][rt * 16 + hi * 4 + i] = ss[i];
    }
  }
  __syncthreads();
  if (tid < 64) {
    float s = 0.f;
    #pragma unroll
    for (int ww = 0; ww < 8; ++ww) s += sred[ww][tid];
    sinv[tid] = 1.f / fmaxf(sqrtf(s), 1e-12f);
  }
  __syncthreads();

  // ---- relu + dual LDS store + fused pool (layer 3) ----
  unsigned char* sQ = (unsigned char*)sH;
  #pragma unroll
  for (int rt = 0; rt < 4; ++rt) {
    float vm = 0.f;
    #pragma unroll
    for (int i = 0; i < 4; ++i) {
      int row = rt * 16 + hi * 4 + i;
      float r = fmaxf(v[rt][i] * sinv[row], 0.f);
      vm = fmaxf(vm, r);
      if (doout) {
        sAgg[row * 128 + ((w ^ (row & 7)) * 16) + l16] = f2b(r);
        int e8 = __builtin_amdgcn_cvt_pk_fp8_f32(r, r, 0, false);
        sQ[row * 128 + ((w ^ (row & 7)) * 16) + l16] = (unsigned char)(e8 & 0xFF);
      }
    }
    if (hgmax) {
      int rsb = r0 + rt * 16 + hi * 4;          // 4-row strips never cross graphs
      if (rsb < NN)
        atomicMax((int*)&hgmax[(rsb / 200) * 128 + w * 16 + l16], __float_as_int(vm));
    }
  }
  if (!doout) return;
  __syncthreads();

  // ---- coalesced read-back & store ----
  {
    int rr = tid >> 3, q = tid & 7;
    int row = r0 + rr;
    if (row < NN) {
      int sb = rr * 128 + ((q ^ (rr & 7)) * 16);
      u16x8 p0 = *(const u16x8*)&sAgg[sb];
      u16x8 p1 = *(const u16x8*)&sAgg[sb + 8];
      *(u16x8*)&hout[row * 128 + q * 16] = p0;
      *(u16x8*)&hout[row * 128 + q * 16 + 8] = p1;
      s8x16 pq = *(const s8x16*)&sQ[sb];
      *(s8x16*)&houtq[row * 128 + q * 16] = pq;
    }
  }
}

// ---------- final: news + lin2 + lin3 + sigmoid ----------
__global__ __launch_bounds__(128) void final_k(
    const float* __restrict__ hg, const int* __restrict__ root,
    const float* __restrict__ x,
    const float* __restrict__ Wn, const float* __restrict__ bn,
    const float* __restrict__ W2, const float* __restrict__ b2,
    const float* __restrict__ W3, const float* __restrict__ b3,
    float* __restrict__ out) {
  __shared__ float hgr[128];
  __shared__ float xr[128];
  __shared__ float red[2];
  int g = blockIdx.x, j = threadIdx.x;
  int rt = root[g];
  hgr[j] = hg[g * HH + j];
  xr[j] = x[rt * HH + j];
  __syncthreads();
  float acc2 = b2[j];
  float accn = bn[j];
  for (int k = 0; k < 128; ++k) {
    acc2 += hgr[k] * W2[k * HH + j];
    accn += xr[k] * Wn[k * HH + j];
  }
  float c = fmaxf(acc2, 0.f) * W3[j] + fmaxf(accn, 0.f) * W3[HH + j];
  #pragma unroll
  for (int d = 1; d < 64; d <<= 1) c += __shfl_xor(c, d);
  if ((j & 63) == 0) red[j >> 6] = c;
  __syncthreads();
  if (j == 0) out[g] = 1.f / (1.f + expf(-(red[0] + red[1] + b3[0])));
}

extern "C" void kernel_launch(void* const* d_in, const int* in_sizes, int n_in,
                              void* d_out, int out_size, void* d_ws, size_t ws_size,
                              hipStream_t stream) {
  const float* x     = (const float*)d_in[0];
  const int*   adj   = (const int*)d_in[1];
  const int*   batch = (const int*)d_in[2];
  const float *W1l = (const float*)d_in[3],  *b1l = (const float*)d_in[4],  *W1r = (const float*)d_in[5];
  const float *W2l = (const float*)d_in[6],  *b2l = (const float*)d_in[7],  *W2r = (const float*)d_in[8];
  const float *W3l = (const float*)d_in[9],  *b3l = (const float*)d_in[10], *W3r = (const float*)d_in[11];
  const float *Wnews = (const float*)d_in[12], *bnews = (const float*)d_in[13];
  const float *Wlin2 = (const float*)d_in[14], *blin2 = (const float*)d_in[15];
  const float *Wlin3 = (const float*)d_in[16], *blin3 = (const float*)d_in[17];
  float* out = (float*)d_out;

  const int* srcp = adj;
  const int* dstp = adj + EE;

  char* ws = (char*)d_ws;
  size_t off = 0;
  auto alloc = [&](size_t bytes) -> void* {
    void* p = ws + off;
    off = (off + bytes + 255) & ~(size_t)255;
    return p;
  };
  int*   deg    = (int*)alloc(sizeof(int) * NN);
  int*   excl   = (int*)alloc(sizeof(int) * NN);
  int*   bsum   = (int*)alloc(sizeof(int) * 64);
  int*   rowptr = (int*)alloc(sizeof(int) * (NN + 1));
  int*   wp     = (int*)alloc(sizeof(int) * NN);
  int*   root   = (int*)alloc(sizeof(int) * GG);
  int*   eidx   = (int*)alloc(sizeof(int) * EE);
  unsigned short* WT = (unsigned short*)alloc(sizeof(short) * 6 * 128 * 128);
  unsigned short* xb = (unsigned short*)alloc(sizeof(short) * NN * HH);
  unsigned short* h1 = (unsigned short*)alloc(sizeof(short) * NN * HH);
  unsigned short* h2 = (unsigned short*)alloc(sizeof(short) * NN * HH);
  unsigned char* xq = (unsigned char*)alloc(NN * HH);
  unsigned char* q1 = (unsigned char*)alloc(NN * HH);
  unsigned char* q2 = (unsigned char*)alloc(NN * HH);
  float* hg = (float*)alloc(sizeof(float) * GG * HH);
  (void)ws_size; (void)n_in; (void)in_sizes; (void)out_size;

  prep_k<<<B_CVT + B_W + B_ROOT + B_ZD + B_ZH, 256, 0, stream>>>(
      x, xb, xq, W1l, W1r, W2l, W2r, W3l, W3r, WT, deg, batch, root, hg);
  hist_k<<<(EE + 255) / 256, 256, 0, stream>>>(dstp, deg);
  scan1_k<<<(NN + 1023) / 1024, 1024, 0, stream>>>(deg, excl, bsum);
  scanB_k<<<(NN + 255) / 256, 256, 0, stream>>>(excl, bsum, rowptr, wp);
  scatter_k<<<(EE + 255) / 256, 256, 0, stream>>>(srcp, dstp, wp, eidx);

  const int LGRID = (NN + 63) / 64;          // 782

  layer_k<<<LGRID, 512, 0, stream>>>(xb, xq, rowptr, eidx,
                                     WT + 0 * 32768, b1l, h1, q1, nullptr);
  layer_k<<<LGRID, 512, 0, stream>>>(h1, q1, rowptr, eidx,
                                     WT + 1 * 32768, b2l, h2, q2, nullptr);
  layer_k<<<LGRID, 512, 0, stream>>>(h2, q2, rowptr, eidx,
                                     WT + 2 * 32768, b3l, nullptr, nullptr, hg);

  final_k<<<GG, 128, 0, stream>>>(hg, root, x, Wnews, bnews,
                                  Wlin2, blin2, Wlin3, blin3, out);
}

// Round 18
// 229.994 us; speedup vs baseline: 1.0513x; 1.0513x over previous
//
#include <hip/hip_runtime.h>
#include <math.h>

#define NN 50000
#define EE 600000
#define GG 250
#define HH 128

// prep_k grid split
#define B_CVT  6250
#define B_W    384
#define B_ROOT 196
#define B_ZD   196
#define B_ZH   125

typedef __attribute__((ext_vector_type(8))) short s16x8;
typedef __attribute__((ext_vector_type(8))) unsigned short u16x8;
typedef __attribute__((ext_vector_type(4))) unsigned short u16x4;
typedef __attribute__((ext_vector_type(16))) signed char s8x16;
typedef __attribute__((ext_vector_type(4))) float f32x4;
typedef __attribute__((ext_vector_type(2))) float f32x2;

__device__ __forceinline__ float b2f(unsigned short u) {
  union { unsigned int i; float f; } v; v.i = ((unsigned int)u) << 16; return v.f;
}
__device__ __forceinline__ unsigned short f2b(float f) {
  union { float f; unsigned int i; } v; v.f = f;
  unsigned int x = v.i;
  unsigned int r = (x + 0x7FFFu + ((x >> 16) & 1u)) >> 16;   // RNE, finite inputs
  return (unsigned short)r;
}

// ---------- fused prep: cvt_x(bf16+fp8) | cvtW(frag layout) | root | zero-deg | zero-hg ----------
// WT2 layout: idx = L*32768 + w*4096 + m*2048 + kk*512 + lane*8 + j
__global__ __launch_bounds__(256) void prep_k(
    const float* __restrict__ x, unsigned short* __restrict__ xb,
    unsigned char* __restrict__ xq,
    const float* __restrict__ W0, const float* __restrict__ W1,
    const float* __restrict__ W2, const float* __restrict__ W3,
    const float* __restrict__ W4, const float* __restrict__ W5,
    unsigned short* __restrict__ WT,
    int* __restrict__ deg,
    const int* __restrict__ batch, int* __restrict__ root,
    float* __restrict__ hg) {
  int b = blockIdx.x, tid = threadIdx.x;
  if (b < B_CVT) {
    int i = b * 256 + tid;                       // x4 floats
    float4 v = *(const float4*)&x[i * 4];
    u16x4 o; o[0] = f2b(v.x); o[1] = f2b(v.y); o[2] = f2b(v.z); o[3] = f2b(v.w);
    *(u16x4*)&xb[i * 4] = o;
    int pk = __builtin_amdgcn_cvt_pk_fp8_f32(v.x, v.y, 0, false);
    pk = __builtin_amdgcn_cvt_pk_fp8_f32(v.z, v.w, pk, true);
    *(int*)&xq[i * 4] = pk;
  } else if (b < B_CVT + B_W) {
    int i = (b - B_CVT) * 256 + tid;             // 0..98303
    int j = i & 7, lane = (i >> 3) & 63, kk = (i >> 9) & 3;
    int m = (i >> 11) & 1, w = (i >> 12) & 7, L = i >> 15;
    int sel = L * 2 + m;
    const float* W = (sel == 0) ? W0 : (sel == 1) ? W1 : (sel == 2) ? W2
                     : (sel == 3) ? W3 : (sel == 4) ? W4 : W5;
    int col = w * 16 + (lane & 15);
    int k = kk * 32 + ((lane >> 4) & 3) * 8 + j;
    WT[i] = f2b(W[k * 128 + col]);
  } else if (b < B_CVT + B_W + B_ROOT) {
    int n = (b - B_CVT - B_W) * 256 + tid;
    if (n < NN) {
      int bg = batch[n];
      if (n == 0 || batch[n - 1] != bg) root[bg] = n;
    }
  } else if (b < B_CVT + B_W + B_ROOT + B_ZD) {
    int n = (b - B_CVT - B_W - B_ROOT) * 256 + tid;
    if (n < NN) deg[n] = 0;
  } else {
    int i = (b - B_CVT - B_W - B_ROOT - B_ZD) * 256 + tid;   // < 32000
    hg[i] = 0.f;
  }
}

// ---------- histogram ----------
__global__ void hist_k(const int* __restrict__ dst, int* __restrict__ deg) {
  int e = blockIdx.x * 256 + threadIdx.x;
  if (e < EE) atomicAdd(&deg[dst[e]], 1);
}

// ---------- scan, phase 1 ----------
__global__ __launch_bounds__(1024) void scan1_k(const int* __restrict__ deg,
                                                int* __restrict__ excl,
                                                int* __restrict__ bsum) {
  __shared__ int sums[16];
  int tid = threadIdx.x;
  int i = blockIdx.x * 1024 + tid;
  int v = (i < NN) ? deg[i] : 0;
  int lane = tid & 63, wid = tid >> 6;
  int x = v;
  #pragma unroll
  for (int d = 1; d < 64; d <<= 1) { int y = __shfl_up(x, d); if (lane >= d) x += y; }
  if (lane == 63) sums[wid] = x;
  __syncthreads();
  if (wid == 0) {
    int s = (lane < 16) ? sums[lane] : 0;
    #pragma unroll
    for (int d = 1; d < 16; d <<= 1) { int y = __shfl_up(s, d); if (lane >= d) s += y; }
    if (lane < 16) sums[lane] = s;
  }
  __syncthreads();
  int ex = (wid ? sums[wid - 1] : 0) + x - v;
  if (i < NN) excl[i] = ex;
  if (tid == 1023) bsum[blockIdx.x] = sums[15];
}

// ---------- scan, phase 2+3 fused ----------
__global__ __launch_bounds__(256) void scanB_k(const int* __restrict__ excl,
                                               const int* __restrict__ bsum,
                                               int* __restrict__ rowptr,
                                               int* __restrict__ wp) {
  __shared__ int sboff[64];
  int tid = threadIdx.x;
  if (tid < 64) {
    int v = (tid < 49) ? bsum[tid] : 0;
    int x = v;
    #pragma unroll
    for (int d = 1; d < 64; d <<= 1) { int y = __shfl_up(x, d); if (tid >= d) x += y; }
    sboff[tid] = x - v;
  }
  __syncthreads();
  int i = blockIdx.x * 256 + tid;
  if (i < NN) {
    int r = excl[i] + sboff[i >> 10];
    rowptr[i] = r; wp[i] = r;
  }
  if (i == 0) rowptr[NN] = EE;
}

__global__ void scatter_k(const int* __restrict__ src, const int* __restrict__ dst,
                          int* __restrict__ wp, int* __restrict__ eidx) {
  int e = blockIdx.x * 256 + threadIdx.x;
  if (e < EE) {
    int p = atomicAdd(&wp[dst[e]], 1);
    eidx[p] = src[e];
  }
}

// ---------- fused layer: fp8 8-deep gather-mean -> LDS, MFMA, L2norm, relu, dual store ----------
// 512 threads / 8 waves / 64 rows. Gather reads fp8 e4m3 rows (128B, 8B/lane),
// 8 row-loads in flight per group (16 staging VGPRs, total ~60 < 64 cliff).
// Self path bf16. Outputs bf16 (next self) + fp8 (next gather).
// Layer 3: hout=nullptr -> pool only, no stores.
__global__ __launch_bounds__(512) void layer_k(
    const unsigned short* __restrict__ hb,
    const unsigned char* __restrict__ hq,
    const int* __restrict__ rowptr, const int* __restrict__ eidx,
    const unsigned short* __restrict__ WT2, const float* __restrict__ bl,
    unsigned short* __restrict__ hout, unsigned char* __restrict__ houtq,
    float* __restrict__ hgmax) {
  __shared__ unsigned short sAgg[64 * 128];   // 16 KB (reused as bf16 out)
  __shared__ unsigned short sH[64 * 128];     // 16 KB (reused as fp8 out)
  __shared__ float sred[8][64];
  __shared__ float sinv[64];
  int tid = threadIdx.x;
  int r0 = blockIdx.x * 64;
  int lane = tid & 63, w = tid >> 6;
  int l16 = lane & 15, hi = lane >> 4;
  bool doout = (hout != nullptr);

  // ---- weights & bias (issue first) ----
  s16x8 wf[8];
  #pragma unroll
  for (int f = 0; f < 8; ++f)
    wf[f] = *(const s16x8*)&WT2[w * 4096 + f * 512 + lane * 8];
  float bb = bl[w * 16 + l16];

  // ---- gather phase: 32 groups of 16 lanes, 2 nodes each; 8 loads in flight ----
  {
    int gid = tid >> 4, gl = tid & 15;
    #pragma unroll 1
    for (int s = 0; s < 2; ++s) {
      int rl = gid * 2 + s;
      int node = r0 + rl; if (node > NN - 1) node = NN - 1;
      int st = rowptr[node], en = rowptr[node + 1];
      u16x8 own = *(const u16x8*)&hb[node * 128 + gl * 8];
      *(u16x8*)&sH[rl * 128 + ((gl ^ (rl & 7)) * 8)] = own;
      float acc[8] = {0.f, 0.f, 0.f, 0.f, 0.f, 0.f, 0.f, 0.f};
      for (int e = st; e < en; e += 8) {
        int se[8];
        #pragma unroll
        for (int t = 0; t < 8; ++t) {
          int ei = e + t; if (ei > en - 1) ei = en - 1;
          se[t] = eidx[ei];                   // uniform in group -> broadcast
        }
        uint2 rv[8];
        #pragma unroll
        for (int t = 0; t < 8; ++t)
          rv[t] = *(const uint2*)&hq[se[t] * 128 + gl * 8];   // 8 in flight
        #pragma unroll
        for (int t = 0; t < 8; ++t) {
          float mk = (e + t < en) ? 1.f : 0.f;
          f32x2 p0;
          p0 = __builtin_amdgcn_cvt_pk_f32_fp8(rv[t].x, false);
          acc[0] = fmaf(mk, p0.x, acc[0]);  acc[1] = fmaf(mk, p0.y, acc[1]);
          p0 = __builtin_amdgcn_cvt_pk_f32_fp8(rv[t].x, true);
          acc[2] = fmaf(mk, p0.x, acc[2]);  acc[3] = fmaf(mk, p0.y, acc[3]);
          p0 = __builtin_amdgcn_cvt_pk_f32_fp8(rv[t].y, false);
          acc[4] = fmaf(mk, p0.x, acc[4]);  acc[5] = fmaf(mk, p0.y, acc[5]);
          p0 = __builtin_amdgcn_cvt_pk_f32_fp8(rv[t].y, true);
          acc[6] = fmaf(mk, p0.x, acc[6]);  acc[7] = fmaf(mk, p0.y, acc[7]);
        }
      }
      int cnt = en - st;
      float inv = 1.f / (float)(cnt > 0 ? cnt : 1);
      u16x8 o;
      #pragma unroll
      for (int j = 0; j < 8; ++j) o[j] = f2b(acc[j] * inv);
      *(u16x8*)&sAgg[rl * 128 + ((gl ^ (rl & 7)) * 8)] = o;
    }
  }
  __syncthreads();

  // ---- MFMA: 4 row-tiles x this wave's col-tile ----
  f32x4 acc[4];
  #pragma unroll
  for (int rt = 0; rt < 4; ++rt) acc[rt] = (f32x4){0.f, 0.f, 0.f, 0.f};
  #pragma unroll
  for (int kk = 0; kk < 4; ++kk) {
    int au = ((kk * 4 + hi) ^ (l16 & 7)) * 8;
    #pragma unroll
    for (int rt = 0; rt < 4; ++rt) {
      s16x8 a = *(const s16x8*)&sAgg[(rt * 16 + l16) * 128 + au];
      s16x8 h = *(const s16x8*)&sH[(rt * 16 + l16) * 128 + au];
      acc[rt] = __builtin_amdgcn_mfma_f32_16x16x32_bf16(a, wf[kk], acc[rt], 0, 0, 0);
      acc[rt] = __builtin_amdgcn_mfma_f32_16x16x32_bf16(h, wf[4 + kk], acc[rt], 0, 0, 0);
    }
  }

  // ---- bias + partial row-norm (this wave's 16 cols) ----
  float v[4][4];
  #pragma unroll
  for (int rt = 0; rt < 4; ++rt) {
    float ss[4];
    #pragma unroll
    for (int i = 0; i < 4; ++i) {
      float t = acc[rt][i] + bb;
      v[rt][i] = t;
      ss[i] = t * t;
    }
    #pragma unroll
    for (int m = 1; m < 16; m <<= 1) {
      #pragma unroll
      for (int i = 0; i < 4; ++i) ss[i] += __shfl_xor(ss[i], m);
    }
    if (l16 == 0) {
      #pragma unroll
      for (int i = 0; i < 4; ++i) sred[w][rt * 16 + hi * 4 + i] = ss[i];
    }
  }
  __syncthreads();
  if (tid < 64) {
    float s = 0.f;
    #pragma unroll
    for (int ww = 0; ww < 8; ++ww) s += sred[ww][tid];
    sinv[tid] = 1.f / fmaxf(sqrtf(s), 1e-12f);
  }
  __syncthreads();

  // ---- relu + dual LDS store + fused pool (layer 3) ----
  unsigned char* sQ = (unsigned char*)sH;
  #pragma unroll
  for (int rt = 0; rt < 4; ++rt) {
    float vm = 0.f;
    #pragma unroll
    for (int i = 0; i < 4; ++i) {
      int row = rt * 16 + hi * 4 + i;
      float r = fmaxf(v[rt][i] * sinv[row], 0.f);
      vm = fmaxf(vm, r);
      if (doout) {
        sAgg[row * 128 + ((w ^ (row & 7)) * 16) + l16] = f2b(r);
        int e8 = __builtin_amdgcn_cvt_pk_fp8_f32(r, r, 0, false);
        sQ[row * 128 + ((w ^ (row & 7)) * 16) + l16] = (unsigned char)(e8 & 0xFF);
      }
    }
    if (hgmax) {
      int rsb = r0 + rt * 16 + hi * 4;          // 4-row strips never cross graphs
      if (rsb < NN)
        atomicMax((int*)&hgmax[(rsb / 200) * 128 + w * 16 + l16], __float_as_int(vm));
    }
  }
  if (!doout) return;
  __syncthreads();

  // ---- coalesced read-back & store ----
  {
    int rr = tid >> 3, q = tid & 7;
    int row = r0 + rr;
    if (row < NN) {
      int sb = rr * 128 + ((q ^ (rr & 7)) * 16);
      u16x8 p0 = *(const u16x8*)&sAgg[sb];
      u16x8 p1 = *(const u16x8*)&sAgg[sb + 8];
      *(u16x8*)&hout[row * 128 + q * 16] = p0;
      *(u16x8*)&hout[row * 128 + q * 16 + 8] = p1;
      s8x16 pq = *(const s8x16*)&sQ[sb];
      *(s8x16*)&houtq[row * 128 + q * 16] = pq;
    }
  }
}

// ---------- final: news + lin2 + lin3 + sigmoid ----------
__global__ __launch_bounds__(128) void final_k(
    const float* __restrict__ hg, const int* __restrict__ root,
    const float* __restrict__ x,
    const float* __restrict__ Wn, const float* __restrict__ bn,
    const float* __restrict__ W2, const float* __restrict__ b2,
    const float* __restrict__ W3, const float* __restrict__ b3,
    float* __restrict__ out) {
  __shared__ float hgr[128];
  __shared__ float xr[128];
  __shared__ float red[2];
  int g = blockIdx.x, j = threadIdx.x;
  int rt = root[g];
  hgr[j] = hg[g * HH + j];
  xr[j] = x[rt * HH + j];
  __syncthreads();
  float acc2 = b2[j];
  float accn = bn[j];
  for (int k = 0; k < 128; ++k) {
    acc2 += hgr[k] * W2[k * HH + j];
    accn += xr[k] * Wn[k * HH + j];
  }
  float c = fmaxf(acc2, 0.f) * W3[j] + fmaxf(accn, 0.f) * W3[HH + j];
  #pragma unroll
  for (int d = 1; d < 64; d <<= 1) c += __shfl_xor(c, d);
  if ((j & 63) == 0) red[j >> 6] = c;
  __syncthreads();
  if (j == 0) out[g] = 1.f / (1.f + expf(-(red[0] + red[1] + b3[0])));
}

extern "C" void kernel_launch(void* const* d_in, const int* in_sizes, int n_in,
                              void* d_out, int out_size, void* d_ws, size_t ws_size,
                              hipStream_t stream) {
  const float* x     = (const float*)d_in[0];
  const int*   adj   = (const int*)d_in[1];
  const int*   batch = (const int*)d_in[2];
  const float *W1l = (const float*)d_in[3],  *b1l = (const float*)d_in[4],  *W1r = (const float*)d_in[5];
  const float *W2l = (const float*)d_in[6],  *b2l = (const float*)d_in[7],  *W2r = (const float*)d_in[8];
  const float *W3l = (const float*)d_in[9],  *b3l = (const float*)d_in[10], *W3r = (const float*)d_in[11];
  const float *Wnews = (const float*)d_in[12], *bnews = (const float*)d_in[13];
  const float *Wlin2 = (const float*)d_in[14], *blin2 = (const float*)d_in[15];
  const float *Wlin3 = (const float*)d_in[16], *blin3 = (const float*)d_in[17];
  float* out = (float*)d_out;

  const int* srcp = adj;
  const int* dstp = adj + EE;

  char* ws = (char*)d_ws;
  size_t off = 0;
  auto alloc = [&](size_t bytes) -> void* {
    void* p = ws + off;
    off = (off + bytes + 255) & ~(size_t)255;
    return p;
  };
  int*   deg    = (int*)alloc(sizeof(int) * NN);
  int*   excl   = (int*)alloc(sizeof(int) * NN);
  int*   bsum   = (int*)alloc(sizeof(int) * 64);
  int*   rowptr = (int*)alloc(sizeof(int) * (NN + 1));
  int*   wp     = (int*)alloc(sizeof(int) * NN);
  int*   root   = (int*)alloc(sizeof(int) * GG);
  int*   eidx   = (int*)alloc(sizeof(int) * EE);
  unsigned short* WT = (unsigned short*)alloc(sizeof(short) * 6 * 128 * 128);
  unsigned short* xb = (unsigned short*)alloc(sizeof(short) * NN * HH);
  unsigned short* h1 = (unsigned short*)alloc(sizeof(short) * NN * HH);
  unsigned short* h2 = (unsigned short*)alloc(sizeof(short) * NN * HH);
  unsigned char* xq = (unsigned char*)alloc(NN * HH);
  unsigned char* q1 = (unsigned char*)alloc(NN * HH);
  unsigned char* q2 = (unsigned char*)alloc(NN * HH);
  float* hg = (float*)alloc(sizeof(float) * GG * HH);
  (void)ws_size; (void)n_in; (void)in_sizes; (void)out_size;

  prep_k<<<B_CVT + B_W + B_ROOT + B_ZD + B_ZH, 256, 0, stream>>>(
      x, xb, xq, W1l, W1r, W2l, W2r, W3l, W3r, WT, deg, batch, root, hg);
  hist_k<<<(EE + 255) / 256, 256, 0, stream>>>(dstp, deg);
  scan1_k<<<(NN + 1023) / 1024, 1024, 0, stream>>>(deg, excl, bsum);
  scanB_k<<<(NN + 255) / 256, 256, 0, stream>>>(excl, bsum, rowptr, wp);
  scatter_k<<<(EE + 255) / 256, 256, 0, stream>>>(srcp, dstp, wp, eidx);

  const int LGRID = (NN + 63) / 64;          // 782

  layer_k<<<LGRID, 512, 0, stream>>>(xb, xq, rowptr, eidx,
                                     WT + 0 * 32768, b1l, h1, q1, nullptr);
  layer_k<<<LGRID, 512, 0, stream>>>(h1, q1, rowptr, eidx,
                                     WT + 1 * 32768, b2l, h2, q2, nullptr);
  layer_k<<<LGRID, 512, 0, stream>>>(h2, q2, rowptr, eidx,
                                     WT + 2 * 32768, b3l, nullptr, nullptr, hg);

  final_k<<<GG, 128, 0, stream>>>(hg, root, x, Wnews, bnews,
                                  Wlin2, blin2, Wlin3, blin3, out);
}

// Round 19
// 179.130 us; speedup vs baseline: 1.3499x; 1.2840x over previous
//
#include <hip/hip_runtime.h>
#include <math.h>

#define NN 50000
#define EE 600000
#define GG 250
#define HH 128

// prep_k grid split
#define B_CVT  6250
#define B_W    384
#define B_ROOT 196
#define B_ZD   196
#define B_ZH   125

typedef __attribute__((ext_vector_type(8))) short s16x8;
typedef __attribute__((ext_vector_type(8))) unsigned short u16x8;
typedef __attribute__((ext_vector_type(4))) unsigned short u16x4;
typedef __attribute__((ext_vector_type(16))) signed char s8x16;
typedef __attribute__((ext_vector_type(4))) float f32x4;
typedef __attribute__((ext_vector_type(2))) float f32x2;

__device__ __forceinline__ float b2f(unsigned short u) {
  union { unsigned int i; float f; } v; v.i = ((unsigned int)u) << 16; return v.f;
}
__device__ __forceinline__ unsigned short f2b(float f) {
  union { float f; unsigned int i; } v; v.f = f;
  unsigned int x = v.i;
  unsigned int r = (x + 0x7FFFu + ((x >> 16) & 1u)) >> 16;   // RNE, finite inputs
  return (unsigned short)r;
}

// ---------- fused prep: cvt_x(bf16+fp8) | cvtW(frag layout) | root | zero-deg | zero-hg ----------
// WT2 layout: idx = L*32768 + w*4096 + m*2048 + kk*512 + lane*8 + j
__global__ __launch_bounds__(256) void prep_k(
    const float* __restrict__ x, unsigned short* __restrict__ xb,
    unsigned char* __restrict__ xq,
    const float* __restrict__ W0, const float* __restrict__ W1,
    const float* __restrict__ W2, const float* __restrict__ W3,
    const float* __restrict__ W4, const float* __restrict__ W5,
    unsigned short* __restrict__ WT,
    int* __restrict__ deg,
    const int* __restrict__ batch, int* __restrict__ root,
    float* __restrict__ hg) {
  int b = blockIdx.x, tid = threadIdx.x;
  if (b < B_CVT) {
    int i = b * 256 + tid;                       // x4 floats
    float4 v = *(const float4*)&x[i * 4];
    u16x4 o; o[0] = f2b(v.x); o[1] = f2b(v.y); o[2] = f2b(v.z); o[3] = f2b(v.w);
    *(u16x4*)&xb[i * 4] = o;
    int pk = __builtin_amdgcn_cvt_pk_fp8_f32(v.x, v.y, 0, false);
    pk = __builtin_amdgcn_cvt_pk_fp8_f32(v.z, v.w, pk, true);
    *(int*)&xq[i * 4] = pk;
  } else if (b < B_CVT + B_W) {
    int i = (b - B_CVT) * 256 + tid;             // 0..98303
    int j = i & 7, lane = (i >> 3) & 63, kk = (i >> 9) & 3;
    int m = (i >> 11) & 1, w = (i >> 12) & 7, L = i >> 15;
    int sel = L * 2 + m;
    const float* W = (sel == 0) ? W0 : (sel == 1) ? W1 : (sel == 2) ? W2
                     : (sel == 3) ? W3 : (sel == 4) ? W4 : W5;
    int col = w * 16 + (lane & 15);
    int k = kk * 32 + ((lane >> 4) & 3) * 8 + j;
    WT[i] = f2b(W[k * 128 + col]);
  } else if (b < B_CVT + B_W + B_ROOT) {
    int n = (b - B_CVT - B_W) * 256 + tid;
    if (n < NN) {
      int bg = batch[n];
      if (n == 0 || batch[n - 1] != bg) root[bg] = n;
    }
  } else if (b < B_CVT + B_W + B_ROOT + B_ZD) {
    int n = (b - B_CVT - B_W - B_ROOT) * 256 + tid;
    if (n < NN) deg[n] = 0;
  } else {
    int i = (b - B_CVT - B_W - B_ROOT - B_ZD) * 256 + tid;   // < 32000
    hg[i] = 0.f;
  }
}

// ---------- histogram ----------
__global__ void hist_k(const int* __restrict__ dst, int* __restrict__ deg) {
  int e = blockIdx.x * 256 + threadIdx.x;
  if (e < EE) atomicAdd(&deg[dst[e]], 1);
}

// ---------- scan, phase 1 ----------
__global__ __launch_bounds__(1024) void scan1_k(const int* __restrict__ deg,
                                                int* __restrict__ excl,
                                                int* __restrict__ bsum) {
  __shared__ int sums[16];
  int tid = threadIdx.x;
  int i = blockIdx.x * 1024 + tid;
  int v = (i < NN) ? deg[i] : 0;
  int lane = tid & 63, wid = tid >> 6;
  int x = v;
  #pragma unroll
  for (int d = 1; d < 64; d <<= 1) { int y = __shfl_up(x, d); if (lane >= d) x += y; }
  if (lane == 63) sums[wid] = x;
  __syncthreads();
  if (wid == 0) {
    int s = (lane < 16) ? sums[lane] : 0;
    #pragma unroll
    for (int d = 1; d < 16; d <<= 1) { int y = __shfl_up(s, d); if (lane >= d) s += y; }
    if (lane < 16) sums[lane] = s;
  }
  __syncthreads();
  int ex = (wid ? sums[wid - 1] : 0) + x - v;
  if (i < NN) excl[i] = ex;
  if (tid == 1023) bsum[blockIdx.x] = sums[15];
}

// ---------- scan, phase 2+3 fused ----------
__global__ __launch_bounds__(256) void scanB_k(const int* __restrict__ excl,
                                               const int* __restrict__ bsum,
                                               int* __restrict__ rowptr,
                                               int* __restrict__ wp) {
  __shared__ int sboff[64];
  int tid = threadIdx.x;
  if (tid < 64) {
    int v = (tid < 49) ? bsum[tid] : 0;
    int x = v;
    #pragma unroll
    for (int d = 1; d < 64; d <<= 1) { int y = __shfl_up(x, d); if (tid >= d) x += y; }
    sboff[tid] = x - v;
  }
  __syncthreads();
  int i = blockIdx.x * 256 + tid;
  if (i < NN) {
    int r = excl[i] + sboff[i >> 10];
    rowptr[i] = r; wp[i] = r;
  }
  if (i == 0) rowptr[NN] = EE;
}

__global__ void scatter_k(const int* __restrict__ src, const int* __restrict__ dst,
                          int* __restrict__ wp, int* __restrict__ eidx) {
  int e = blockIdx.x * 256 + threadIdx.x;
  if (e < EE) {
    int p = atomicAdd(&wp[dst[e]], 1);
    eidx[p] = src[e];
  }
}

// ---------- fused layer: fp8 8-deep gather-mean -> LDS, MFMA, L2norm, relu, dual store ----------
// 512 threads / 8 waves / 64 rows. __launch_bounds__(512,8) pins VGPR <= 64.
// Weight fragments loaded AFTER the gather barrier (not live through gather).
// Layer 3: hout=nullptr -> pool only, no stores.
__global__ __launch_bounds__(512, 8) void layer_k(
    const unsigned short* __restrict__ hb,
    const unsigned char* __restrict__ hq,
    const int* __restrict__ rowptr, const int* __restrict__ eidx,
    const unsigned short* __restrict__ WT2, const float* __restrict__ bl,
    unsigned short* __restrict__ hout, unsigned char* __restrict__ houtq,
    float* __restrict__ hgmax) {
  __shared__ unsigned short sAgg[64 * 128];   // 16 KB (reused as bf16 out)
  __shared__ unsigned short sH[64 * 128];     // 16 KB (reused as fp8 out)
  __shared__ float sred[8][64];
  __shared__ float sinv[64];
  int tid = threadIdx.x;
  int r0 = blockIdx.x * 64;
  int lane = tid & 63, w = tid >> 6;
  int l16 = lane & 15, hi = lane >> 4;
  bool doout = (hout != nullptr);

  // ---- gather phase: 32 groups of 16 lanes, 2 nodes each; 8 loads in flight ----
  {
    int gid = tid >> 4, gl = tid & 15;
    #pragma unroll 1
    for (int s = 0; s < 2; ++s) {
      int rl = gid * 2 + s;
      int node = r0 + rl; if (node > NN - 1) node = NN - 1;
      int st = rowptr[node], en = rowptr[node + 1];
      u16x8 own = *(const u16x8*)&hb[node * 128 + gl * 8];
      *(u16x8*)&sH[rl * 128 + ((gl ^ (rl & 7)) * 8)] = own;
      float acc[8] = {0.f, 0.f, 0.f, 0.f, 0.f, 0.f, 0.f, 0.f};
      for (int e = st; e < en; e += 8) {
        int se[8];
        #pragma unroll
        for (int t = 0; t < 8; ++t) {
          int ei = e + t; if (ei > en - 1) ei = en - 1;
          se[t] = eidx[ei];                   // uniform in group -> broadcast
        }
        uint2 rv[8];
        #pragma unroll
        for (int t = 0; t < 8; ++t)
          rv[t] = *(const uint2*)&hq[se[t] * 128 + gl * 8];   // 8 in flight
        #pragma unroll
        for (int t = 0; t < 8; ++t) {
          float mk = (e + t < en) ? 1.f : 0.f;
          f32x2 p0;
          p0 = __builtin_amdgcn_cvt_pk_f32_fp8(rv[t].x, false);
          acc[0] = fmaf(mk, p0.x, acc[0]);  acc[1] = fmaf(mk, p0.y, acc[1]);
          p0 = __builtin_amdgcn_cvt_pk_f32_fp8(rv[t].x, true);
          acc[2] = fmaf(mk, p0.x, acc[2]);  acc[3] = fmaf(mk, p0.y, acc[3]);
          p0 = __builtin_amdgcn_cvt_pk_f32_fp8(rv[t].y, false);
          acc[4] = fmaf(mk, p0.x, acc[4]);  acc[5] = fmaf(mk, p0.y, acc[5]);
          p0 = __builtin_amdgcn_cvt_pk_f32_fp8(rv[t].y, true);
          acc[6] = fmaf(mk, p0.x, acc[6]);  acc[7] = fmaf(mk, p0.y, acc[7]);
        }
      }
      int cnt = en - st;
      float inv = 1.f / (float)(cnt > 0 ? cnt : 1);
      u16x8 o;
      #pragma unroll
      for (int j = 0; j < 8; ++j) o[j] = f2b(acc[j] * inv);
      *(u16x8*)&sAgg[rl * 128 + ((gl ^ (rl & 7)) * 8)] = o;
    }
  }
  __syncthreads();

  // ---- weights & bias (loaded AFTER gather: not live through it) ----
  s16x8 wf[8];
  #pragma unroll
  for (int f = 0; f < 8; ++f)
    wf[f] = *(const s16x8*)&WT2[w * 4096 + f * 512 + lane * 8];
  float bb = bl[w * 16 + l16];

  // ---- MFMA: 4 row-tiles x this wave's col-tile ----
  f32x4 acc[4];
  #pragma unroll
  for (int rt = 0; rt < 4; ++rt) acc[rt] = (f32x4){0.f, 0.f, 0.f, 0.f};
  #pragma unroll
  for (int kk = 0; kk < 4; ++kk) {
    int au = ((kk * 4 + hi) ^ (l16 & 7)) * 8;
    #pragma unroll
    for (int rt = 0; rt < 4; ++rt) {
      s16x8 a = *(const s16x8*)&sAgg[(rt * 16 + l16) * 128 + au];
      s16x8 h = *(const s16x8*)&sH[(rt * 16 + l16) * 128 + au];
      acc[rt] = __builtin_amdgcn_mfma_f32_16x16x32_bf16(a, wf[kk], acc[rt], 0, 0, 0);
      acc[rt] = __builtin_amdgcn_mfma_f32_16x16x32_bf16(h, wf[4 + kk], acc[rt], 0, 0, 0);
    }
  }

  // ---- bias + partial row-norm (this wave's 16 cols) ----
  float v[4][4];
  #pragma unroll
  for (int rt = 0; rt < 4; ++rt) {
    float ss[4];
    #pragma unroll
    for (int i = 0; i < 4; ++i) {
      float t = acc[rt][i] + bb;
      v[rt][i] = t;
      ss[i] = t * t;
    }
    #pragma unroll
    for (int m = 1; m < 16; m <<= 1) {
      #pragma unroll
      for (int i = 0; i < 4; ++i) ss[i] += __shfl_xor(ss[i], m);
    }
    if (l16 == 0) {
      #pragma unroll
      for (int i = 0; i < 4; ++i) sred[w][rt * 16 + hi * 4 + i] = ss[i];
    }
  }
  __syncthreads();
  if (tid < 64) {
    float s = 0.f;
    #pragma unroll
    for (int ww = 0; ww < 8; ++ww) s += sred[ww][tid];
    sinv[tid] = 1.f / fmaxf(sqrtf(s), 1e-12f);
  }
  __syncthreads();

  // ---- relu + dual LDS store + fused pool (layer 3) ----
  unsigned char* sQ = (unsigned char*)sH;
  #pragma unroll
  for (int rt = 0; rt < 4; ++rt) {
    float vm = 0.f;
    #pragma unroll
    for (int i = 0; i < 4; ++i) {
      int row = rt * 16 + hi * 4 + i;
      float r = fmaxf(v[rt][i] * sinv[row], 0.f);
      vm = fmaxf(vm, r);
      if (doout) {
        sAgg[row * 128 + ((w ^ (row & 7)) * 16) + l16] = f2b(r);
        int e8 = __builtin_amdgcn_cvt_pk_fp8_f32(r, r, 0, false);
        sQ[row * 128 + ((w ^ (row & 7)) * 16) + l16] = (unsigned char)(e8 & 0xFF);
      }
    }
    if (hgmax) {
      int rsb = r0 + rt * 16 + hi * 4;          // 4-row strips never cross graphs
      if (rsb < NN)
        atomicMax((int*)&hgmax[(rsb / 200) * 128 + w * 16 + l16], __float_as_int(vm));
    }
  }
  if (!doout) return;
  __syncthreads();

  // ---- coalesced read-back & store ----
  {
    int rr = tid >> 3, q = tid & 7;
    int row = r0 + rr;
    if (row < NN) {
      int sb = rr * 128 + ((q ^ (rr & 7)) * 16);
      u16x8 p0 = *(const u16x8*)&sAgg[sb];
      u16x8 p1 = *(const u16x8*)&sAgg[sb + 8];
      *(u16x8*)&hout[row * 128 + q * 16] = p0;
      *(u16x8*)&hout[row * 128 + q * 16 + 8] = p1;
      s8x16 pq = *(const s8x16*)&sQ[sb];
      *(s8x16*)&houtq[row * 128 + q * 16] = pq;
    }
  }
}

// ---------- final: news + lin2 + lin3 + sigmoid ----------
__global__ __launch_bounds__(128) void final_k(
    const float* __restrict__ hg, const int* __restrict__ root,
    const float* __restrict__ x,
    const float* __restrict__ Wn, const float* __restrict__ bn,
    const float* __restrict__ W2, const float* __restrict__ b2,
    const float* __restrict__ W3, const float* __restrict__ b3,
    float* __restrict__ out) {
  __shared__ float hgr[128];
  __shared__ float xr[128];
  __shared__ float red[2];
  int g = blockIdx.x, j = threadIdx.x;
  int rt = root[g];
  hgr[j] = hg[g * HH + j];
  xr[j] = x[rt * HH + j];
  __syncthreads();
  float acc2 = b2[j];
  float accn = bn[j];
  for (int k = 0; k < 128; ++k) {
    acc2 += hgr[k] * W2[k * HH + j];
    accn += xr[k] * Wn[k * HH + j];
  }
  float c = fmaxf(acc2, 0.f) * W3[j] + fmaxf(accn, 0.f) * W3[HH + j];
  #pragma unroll
  for (int d = 1; d < 64; d <<= 1) c += __shfl_xor(c, d);
  if ((j & 63) == 0) red[j >> 6] = c;
  __syncthreads();
  if (j == 0) out[g] = 1.f / (1.f + expf(-(red[0] + red[1] + b3[0])));
}

extern "C" void kernel_launch(void* const* d_in, const int* in_sizes, int n_in,
                              void* d_out, int out_size, void* d_ws, size_t ws_size,
                              hipStream_t stream) {
  const float* x     = (const float*)d_in[0];
  const int*   adj   = (const int*)d_in[1];
  const int*   batch = (const int*)d_in[2];
  const float *W1l = (const float*)d_in[3],  *b1l = (const float*)d_in[4],  *W1r = (const float*)d_in[5];
  const float *W2l = (const float*)d_in[6],  *b2l = (const float*)d_in[7],  *W2r = (const float*)d_in[8];
  const float *W3l = (const float*)d_in[9],  *b3l = (const float*)d_in[10], *W3r = (const float*)d_in[11];
  const float *Wnews = (const float*)d_in[12], *bnews = (const float*)d_in[13];
  const float *Wlin2 = (const float*)d_in[14], *blin2 = (const float*)d_in[15];
  const float *Wlin3 = (const float*)d_in[16], *blin3 = (const float*)d_in[17];
  float* out = (float*)d_out;

  const int* srcp = adj;
  const int* dstp = adj + EE;

  char* ws = (char*)d_ws;
  size_t off = 0;
  auto alloc = [&](size_t bytes) -> void* {
    void* p = ws + off;
    off = (off + bytes + 255) & ~(size_t)255;
    return p;
  };
  int*   deg    = (int*)alloc(sizeof(int) * NN);
  int*   excl   = (int*)alloc(sizeof(int) * NN);
  int*   bsum   = (int*)alloc(sizeof(int) * 64);
  int*   rowptr = (int*)alloc(sizeof(int) * (NN + 1));
  int*   wp     = (int*)alloc(sizeof(int) * NN);
  int*   root   = (int*)alloc(sizeof(int) * GG);
  int*   eidx   = (int*)alloc(sizeof(int) * EE);
  unsigned short* WT = (unsigned short*)alloc(sizeof(short) * 6 * 128 * 128);
  unsigned short* xb = (unsigned short*)alloc(sizeof(short) * NN * HH);
  unsigned short* h1 = (unsigned short*)alloc(sizeof(short) * NN * HH);
  unsigned short* h2 = (unsigned short*)alloc(sizeof(short) * NN * HH);
  unsigned char* xq = (unsigned char*)alloc(NN * HH);
  unsigned char* q1 = (unsigned char*)alloc(NN * HH);
  unsigned char* q2 = (unsigned char*)alloc(NN * HH);
  float* hg = (float*)alloc(sizeof(float) * GG * HH);
  (void)ws_size; (void)n_in; (void)in_sizes; (void)out_size;

  prep_k<<<B_CVT + B_W + B_ROOT + B_ZD + B_ZH, 256, 0, stream>>>(
      x, xb, xq, W1l, W1r, W2l, W2r, W3l, W3r, WT, deg, batch, root, hg);
  hist_k<<<(EE + 255) / 256, 256, 0, stream>>>(dstp, deg);
  scan1_k<<<(NN + 1023) / 1024, 1024, 0, stream>>>(deg, excl, bsum);
  scanB_k<<<(NN + 255) / 256, 256, 0, stream>>>(excl, bsum, rowptr, wp);
  scatter_k<<<(EE + 255) / 256, 256, 0, stream>>>(srcp, dstp, wp, eidx);

  const int LGRID = (NN + 63) / 64;          // 782

  layer_k<<<LGRID, 512, 0, stream>>>(xb, xq, rowptr, eidx,
                                     WT + 0 * 32768, b1l, h1, q1, nullptr);
  layer_k<<<LGRID, 512, 0, stream>>>(h1, q1, rowptr, eidx,
                                     WT + 1 * 32768, b2l, h2, q2, nullptr);
  layer_k<<<LGRID, 512, 0, stream>>>(h2, q2, rowptr, eidx,
                                     WT + 2 * 32768, b3l, nullptr, nullptr, hg);

  final_k<<<GG, 128, 0, stream>>>(hg, root, x, Wnews, bnews,
                                  Wlin2, blin2, Wlin3, blin3, out);
}

// Round 20
// 169.245 us; speedup vs baseline: 1.4287x; 1.0584x over previous
//
#include <hip/hip_runtime.h>
#include <math.h>

#define NN 50000
#define EE 600000
#define GG 250
#define HH 128

// prep_k grid split
#define B_CVT  6250
#define B_W    384
#define B_ROOT 196
#define B_ZD   196
#define B_ZH   125

typedef __attribute__((ext_vector_type(8))) short s16x8;
typedef __attribute__((ext_vector_type(8))) unsigned short u16x8;
typedef __attribute__((ext_vector_type(16))) signed char s8x16;
typedef __attribute__((ext_vector_type(4))) float f32x4;
typedef __attribute__((ext_vector_type(2))) float f32x2;

__device__ __forceinline__ float b2f(unsigned short u) {
  union { unsigned int i; float f; } v; v.i = ((unsigned int)u) << 16; return v.f;
}
__device__ __forceinline__ unsigned short f2b(float f) {
  union { float f; unsigned int i; } v; v.f = f;
  unsigned int x = v.i;
  unsigned int r = (x + 0x7FFFu + ((x >> 16) & 1u)) >> 16;   // RNE, finite inputs
  return (unsigned short)r;
}

// ---------- fused prep: cvt_x(fp8) | cvtW(frag layout) | root | zero-deg | zero-hg ----------
// WT2 layout: idx = L*32768 + w*4096 + m*2048 + kk*512 + lane*8 + j
__global__ __launch_bounds__(256) void prep_k(
    const float* __restrict__ x, unsigned char* __restrict__ xq,
    const float* __restrict__ W0, const float* __restrict__ W1,
    const float* __restrict__ W2, const float* __restrict__ W3,
    const float* __restrict__ W4, const float* __restrict__ W5,
    unsigned short* __restrict__ WT,
    int* __restrict__ deg,
    const int* __restrict__ batch, int* __restrict__ root,
    float* __restrict__ hg) {
  int b = blockIdx.x, tid = threadIdx.x;
  if (b < B_CVT) {
    int i = b * 256 + tid;                       // x4 floats
    float4 v = *(const float4*)&x[i * 4];
    int pk = __builtin_amdgcn_cvt_pk_fp8_f32(v.x, v.y, 0, false);
    pk = __builtin_amdgcn_cvt_pk_fp8_f32(v.z, v.w, pk, true);
    *(int*)&xq[i * 4] = pk;
  } else if (b < B_CVT + B_W) {
    int i = (b - B_CVT) * 256 + tid;             // 0..98303
    int j = i & 7, lane = (i >> 3) & 63, kk = (i >> 9) & 3;
    int m = (i >> 11) & 1, w = (i >> 12) & 7, L = i >> 15;
    int sel = L * 2 + m;
    const float* W = (sel == 0) ? W0 : (sel == 1) ? W1 : (sel == 2) ? W2
                     : (sel == 3) ? W3 : (sel == 4) ? W4 : W5;
    int col = w * 16 + (lane & 15);
    int k = kk * 32 + ((lane >> 4) & 3) * 8 + j;
    WT[i] = f2b(W[k * 128 + col]);
  } else if (b < B_CVT + B_W + B_ROOT) {
    int n = (b - B_CVT - B_W) * 256 + tid;
    if (n < NN) {
      int bg = batch[n];
      if (n == 0 || batch[n - 1] != bg) root[bg] = n;
    }
  } else if (b < B_CVT + B_W + B_ROOT + B_ZD) {
    int n = (b - B_CVT - B_W - B_ROOT) * 256 + tid;
    if (n < NN) deg[n] = 0;
  } else {
    int i = (b - B_CVT - B_W - B_ROOT - B_ZD) * 256 + tid;   // < 32000
    hg[i] = 0.f;
  }
}

// ---------- histogram ----------
__global__ void hist_k(const int* __restrict__ dst, int* __restrict__ deg) {
  int e = blockIdx.x * 256 + threadIdx.x;
  if (e < EE) atomicAdd(&deg[dst[e]], 1);
}

// ---------- scan, phase 1 ----------
__global__ __launch_bounds__(1024) void scan1_k(const int* __restrict__ deg,
                                                int* __restrict__ excl,
                                                int* __restrict__ bsum) {
  __shared__ int sums[16];
  int tid = threadIdx.x;
  int i = blockIdx.x * 1024 + tid;
  int v = (i < NN) ? deg[i] : 0;
  int lane = tid & 63, wid = tid >> 6;
  int x = v;
  #pragma unroll
  for (int d = 1; d < 64; d <<= 1) { int y = __shfl_up(x, d); if (lane >= d) x += y; }
  if (lane == 63) sums[wid] = x;
  __syncthreads();
  if (wid == 0) {
    int s = (lane < 16) ? sums[lane] : 0;
    #pragma unroll
    for (int d = 1; d < 16; d <<= 1) { int y = __shfl_up(s, d); if (lane >= d) s += y; }
    if (lane < 16) sums[lane] = s;
  }
  __syncthreads();
  int ex = (wid ? sums[wid - 1] : 0) + x - v;
  if (i < NN) excl[i] = ex;
  if (tid == 1023) bsum[blockIdx.x] = sums[15];
}

// ---------- scan, phase 2+3 fused ----------
__global__ __launch_bounds__(256) void scanB_k(const int* __restrict__ excl,
                                               const int* __restrict__ bsum,
                                               int* __restrict__ rowptr,
                                               int* __restrict__ wp) {
  __shared__ int sboff[64];
  int tid = threadIdx.x;
  if (tid < 64) {
    int v = (tid < 49) ? bsum[tid] : 0;
    int x = v;
    #pragma unroll
    for (int d = 1; d < 64; d <<= 1) { int y = __shfl_up(x, d); if (tid >= d) x += y; }
    sboff[tid] = x - v;
  }
  __syncthreads();
  int i = blockIdx.x * 256 + tid;
  if (i < NN) {
    int r = excl[i] + sboff[i >> 10];
    rowptr[i] = r; wp[i] = r;
  }
  if (i == 0) rowptr[NN] = EE;
}

__global__ void scatter_k(const int* __restrict__ src, const int* __restrict__ dst,
                          int* __restrict__ wp, int* __restrict__ eidx) {
  int e = blockIdx.x * 256 + threadIdx.x;
  if (e < EE) {
    int p = atomicAdd(&wp[dst[e]], 1);
    eidx[p] = src[e];
  }
}

// ---------- fused layer: all-fp8 storage; gather-mean -> LDS, MFMA, L2norm, relu ----------
// 512 threads / 8 waves / 64 rows. __launch_bounds__(512,8) pins VGPR <= 64.
// hq is the ONLY inter-layer tensor (fp8 e4m3, 128B rows). Self path converts
// fp8->bf16 in-register for the MFMA. Layer 3: houtq=nullptr -> pool only.
__global__ __launch_bounds__(512, 8) void layer_k(
    const unsigned char* __restrict__ hq,
    const int* __restrict__ rowptr, const int* __restrict__ eidx,
    const unsigned short* __restrict__ WT2, const float* __restrict__ bl,
    unsigned char* __restrict__ houtq, float* __restrict__ hgmax) {
  __shared__ unsigned short sAgg[64 * 128];   // 16 KB
  __shared__ unsigned short sH[64 * 128];     // 16 KB (reused as fp8 out)
  __shared__ float sred[8][64];
  __shared__ float sinv[64];
  int tid = threadIdx.x;
  int r0 = blockIdx.x * 64;
  int lane = tid & 63, w = tid >> 6;
  int l16 = lane & 15, hi = lane >> 4;
  bool doout = (houtq != nullptr);

  // ---- gather phase: 32 groups of 16 lanes, 2 nodes each; 8 loads in flight ----
  {
    int gid = tid >> 4, gl = tid & 15;
    #pragma unroll 1
    for (int s = 0; s < 2; ++s) {
      int rl = gid * 2 + s;
      int node = r0 + rl; if (node > NN - 1) node = NN - 1;
      int st = rowptr[node], en = rowptr[node + 1];
      // own row: fp8 -> bf16 into sH
      {
        uint2 q = *(const uint2*)&hq[node * 128 + gl * 8];
        f32x2 a0 = __builtin_amdgcn_cvt_pk_f32_fp8(q.x, false);
        f32x2 a1 = __builtin_amdgcn_cvt_pk_f32_fp8(q.x, true);
        f32x2 a2 = __builtin_amdgcn_cvt_pk_f32_fp8(q.y, false);
        f32x2 a3 = __builtin_amdgcn_cvt_pk_f32_fp8(q.y, true);
        u16x8 ob;
        ob[0] = f2b(a0.x); ob[1] = f2b(a0.y); ob[2] = f2b(a1.x); ob[3] = f2b(a1.y);
        ob[4] = f2b(a2.x); ob[5] = f2b(a2.y); ob[6] = f2b(a3.x); ob[7] = f2b(a3.y);
        *(u16x8*)&sH[rl * 128 + ((gl ^ (rl & 7)) * 8)] = ob;
      }
      float acc[8] = {0.f, 0.f, 0.f, 0.f, 0.f, 0.f, 0.f, 0.f};
      for (int e = st; e < en; e += 8) {
        int se[8];
        #pragma unroll
        for (int t = 0; t < 8; ++t) {
          int ei = e + t; if (ei > en - 1) ei = en - 1;
          se[t] = eidx[ei];                   // uniform in group -> broadcast
        }
        uint2 rv[8];
        #pragma unroll
        for (int t = 0; t < 8; ++t)
          rv[t] = *(const uint2*)&hq[se[t] * 128 + gl * 8];   // 8 in flight
        #pragma unroll
        for (int t = 0; t < 8; ++t) {
          float mk = (e + t < en) ? 1.f : 0.f;
          f32x2 p0;
          p0 = __builtin_amdgcn_cvt_pk_f32_fp8(rv[t].x, false);
          acc[0] = fmaf(mk, p0.x, acc[0]);  acc[1] = fmaf(mk, p0.y, acc[1]);
          p0 = __builtin_amdgcn_cvt_pk_f32_fp8(rv[t].x, true);
          acc[2] = fmaf(mk, p0.x, acc[2]);  acc[3] = fmaf(mk, p0.y, acc[3]);
          p0 = __builtin_amdgcn_cvt_pk_f32_fp8(rv[t].y, false);
          acc[4] = fmaf(mk, p0.x, acc[4]);  acc[5] = fmaf(mk, p0.y, acc[5]);
          p0 = __builtin_amdgcn_cvt_pk_f32_fp8(rv[t].y, true);
          acc[6] = fmaf(mk, p0.x, acc[6]);  acc[7] = fmaf(mk, p0.y, acc[7]);
        }
      }
      int cnt = en - st;
      float inv = 1.f / (float)(cnt > 0 ? cnt : 1);
      u16x8 o;
      #pragma unroll
      for (int j = 0; j < 8; ++j) o[j] = f2b(acc[j] * inv);
      *(u16x8*)&sAgg[rl * 128 + ((gl ^ (rl & 7)) * 8)] = o;
    }
  }
  __syncthreads();

  // ---- weights & bias (loaded AFTER gather: not live through it) ----
  s16x8 wf[8];
  #pragma unroll
  for (int f = 0; f < 8; ++f)
    wf[f] = *(const s16x8*)&WT2[w * 4096 + f * 512 + lane * 8];
  float bb = bl[w * 16 + l16];

  // ---- MFMA: 4 row-tiles x this wave's col-tile ----
  f32x4 acc[4];
  #pragma unroll
  for (int rt = 0; rt < 4; ++rt) acc[rt] = (f32x4){0.f, 0.f, 0.f, 0.f};
  #pragma unroll
  for (int kk = 0; kk < 4; ++kk) {
    int au = ((kk * 4 + hi) ^ (l16 & 7)) * 8;
    #pragma unroll
    for (int rt = 0; rt < 4; ++rt) {
      s16x8 a = *(const s16x8*)&sAgg[(rt * 16 + l16) * 128 + au];
      s16x8 h = *(const s16x8*)&sH[(rt * 16 + l16) * 128 + au];
      acc[rt] = __builtin_amdgcn_mfma_f32_16x16x32_bf16(a, wf[kk], acc[rt], 0, 0, 0);
      acc[rt] = __builtin_amdgcn_mfma_f32_16x16x32_bf16(h, wf[4 + kk], acc[rt], 0, 0, 0);
    }
  }

  // ---- bias + partial row-norm (this wave's 16 cols) ----
  float v[4][4];
  #pragma unroll
  for (int rt = 0; rt < 4; ++rt) {
    float ss[4];
    #pragma unroll
    for (int i = 0; i < 4; ++i) {
      float t = acc[rt][i] + bb;
      v[rt][i] = t;
      ss[i] = t * t;
    }
    #pragma unroll
    for (int m = 1; m < 16; m <<= 1) {
      #pragma unroll
      for (int i = 0; i < 4; ++i) ss[i] += __shfl_xor(ss[i], m);
    }
    if (l16 == 0) {
      #pragma unroll
      for (int i = 0; i < 4; ++i) sred[w][rt * 16 + hi * 4 + i] = ss[i];
    }
  }
  __syncthreads();
  if (tid < 64) {
    float s = 0.f;
    #pragma unroll
    for (int ww = 0; ww < 8; ++ww) s += sred[ww][tid];
    sinv[tid] = 1.f / fmaxf(sqrtf(s), 1e-12f);
  }
  __syncthreads();

  // ---- relu + fp8 LDS store + fused pool (layer 3) ----
  unsigned char* sQ = (unsigned char*)sH;
  #pragma unroll
  for (int rt = 0; rt < 4; ++rt) {
    float vm = 0.f;
    #pragma unroll
    for (int i = 0; i < 4; ++i) {
      int row = rt * 16 + hi * 4 + i;
      float r = fmaxf(v[rt][i] * sinv[row], 0.f);
      vm = fmaxf(vm, r);
      if (doout) {
        int e8 = __builtin_amdgcn_cvt_pk_fp8_f32(r, r, 0, false);
        sQ[row * 128 + ((w ^ (row & 7)) * 16) + l16] = (unsigned char)(e8 & 0xFF);
      }
    }
    if (hgmax) {
      int rsb = r0 + rt * 16 + hi * 4;          // 4-row strips never cross graphs
      if (rsb < NN)
        atomicMax((int*)&hgmax[(rsb / 200) * 128 + w * 16 + l16], __float_as_int(vm));
    }
  }
  if (!doout) return;
  __syncthreads();

  // ---- coalesced read-back & store: one 16B/lane instruction ----
  {
    int rr = tid >> 3, q = tid & 7;
    int row = r0 + rr;
    if (row < NN) {
      int sb = rr * 128 + ((q ^ (rr & 7)) * 16);
      s8x16 pq = *(const s8x16*)&sQ[sb];
      *(s8x16*)&houtq[row * 128 + q * 16] = pq;
    }
  }
}

// ---------- final: news + lin2 + lin3 + sigmoid ----------
__global__ __launch_bounds__(128) void final_k(
    const float* __restrict__ hg, const int* __restrict__ root,
    const float* __restrict__ x,
    const float* __restrict__ Wn, const float* __restrict__ bn,
    const float* __restrict__ W2, const float* __restrict__ b2,
    const float* __restrict__ W3, const float* __restrict__ b3,
    float* __restrict__ out) {
  __shared__ float hgr[128];
  __shared__ float xr[128];
  __shared__ float red[2];
  int g = blockIdx.x, j = threadIdx.x;
  int rt = root[g];
  hgr[j] = hg[g * HH + j];
  xr[j] = x[rt * HH + j];
  __syncthreads();
  float acc2 = b2[j];
  float accn = bn[j];
  for (int k = 0; k < 128; ++k) {
    acc2 += hgr[k] * W2[k * HH + j];
    accn += xr[k] * Wn[k * HH + j];
  }
  float c = fmaxf(acc2, 0.f) * W3[j] + fmaxf(accn, 0.f) * W3[HH + j];
  #pragma unroll
  for (int d = 1; d < 64; d <<= 1) c += __shfl_xor(c, d);
  if ((j & 63) == 0) red[j >> 6] = c;
  __syncthreads();
  if (j == 0) out[g] = 1.f / (1.f + expf(-(red[0] + red[1] + b3[0])));
}

extern "C" void kernel_launch(void* const* d_in, const int* in_sizes, int n_in,
                              void* d_out, int out_size, void* d_ws, size_t ws_size,
                              hipStream_t stream) {
  const float* x     = (const float*)d_in[0];
  const int*   adj   = (const int*)d_in[1];
  const int*   batch = (const int*)d_in[2];
  const float *W1l = (const float*)d_in[3],  *b1l = (const float*)d_in[4],  *W1r = (const float*)d_in[5];
  const float *W2l = (const float*)d_in[6],  *b2l = (const float*)d_in[7],  *W2r = (const float*)d_in[8];
  const float *W3l = (const float*)d_in[9],  *b3l = (const float*)d_in[10], *W3r = (const float*)d_in[11];
  const float *Wnews = (const float*)d_in[12], *bnews = (const float*)d_in[13];
  const float *Wlin2 = (const float*)d_in[14], *blin2 = (const float*)d_in[15];
  const float *Wlin3 = (const float*)d_in[16], *blin3 = (const float*)d_in[17];
  float* out = (float*)d_out;

  const int* srcp = adj;
  const int* dstp = adj + EE;

  char* ws = (char*)d_ws;
  size_t off = 0;
  auto alloc = [&](size_t bytes) -> void* {
    void* p = ws + off;
    off = (off + bytes + 255) & ~(size_t)255;
    return p;
  };
  int*   deg    = (int*)alloc(sizeof(int) * NN);
  int*   excl   = (int*)alloc(sizeof(int) * NN);
  int*   bsum   = (int*)alloc(sizeof(int) * 64);
  int*   rowptr = (int*)alloc(sizeof(int) * (NN + 1));
  int*   wp     = (int*)alloc(sizeof(int) * NN);
  int*   root   = (int*)alloc(sizeof(int) * GG);
  int*   eidx   = (int*)alloc(sizeof(int) * EE);
  unsigned short* WT = (unsigned short*)alloc(sizeof(short) * 6 * 128 * 128);
  unsigned char* xq = (unsigned char*)alloc(NN * HH);
  unsigned char* q1 = (unsigned char*)alloc(NN * HH);
  unsigned char* q2 = (unsigned char*)alloc(NN * HH);
  float* hg = (float*)alloc(sizeof(float) * GG * HH);
  (void)ws_size; (void)n_in; (void)in_sizes; (void)out_size;

  prep_k<<<B_CVT + B_W + B_ROOT + B_ZD + B_ZH, 256, 0, stream>>>(
      x, xq, W1l, W1r, W2l, W2r, W3l, W3r, WT, deg, batch, root, hg);
  hist_k<<<(EE + 255) / 256, 256, 0, stream>>>(dstp, deg);
  scan1_k<<<(NN + 1023) / 1024, 1024, 0, stream>>>(deg, excl, bsum);
  scanB_k<<<(NN + 255) / 256, 256, 0, stream>>>(excl, bsum, rowptr, wp);
  scatter_k<<<(EE + 255) / 256, 256, 0, stream>>>(srcp, dstp, wp, eidx);

  const int LGRID = (NN + 63) / 64;          // 782

  layer_k<<<LGRID, 512, 0, stream>>>(xq, rowptr, eidx, WT + 0 * 32768, b1l, q1, nullptr);
  layer_k<<<LGRID, 512, 0, stream>>>(q1, rowptr, eidx, WT + 1 * 32768, b2l, q2, nullptr);
  layer_k<<<LGRID, 512, 0, stream>>>(q2, rowptr, eidx, WT + 2 * 32768, b3l, nullptr, hg);

  final_k<<<GG, 128, 0, stream>>>(hg, root, x, Wnews, bnews,
                                  Wlin2, blin2, Wlin3, blin3, out);
}